// Round 3
// baseline (1312.886 us; speedup 1.0000x reference)
//
#include <hip/hip_runtime.h>

typedef __bf16 bf16;
typedef __bf16 bf16x4 __attribute__((ext_vector_type(4)));
typedef __bf16 bf16x8 __attribute__((ext_vector_type(8)));
typedef float floatx4 __attribute__((ext_vector_type(4)));

#define BB 8
#define LL 2048
#define DD 2048
#define NHH 32
#define HDD 64

#define MFMA16(a, b, c) __builtin_amdgcn_mfma_f32_16x16x32_bf16(a, b, c, 0, 0, 0)

// async global->LDS DMA, 16B per lane; dest = wave-uniform base + lane*16
__device__ __forceinline__ void gl_lds16(const void* g, void* l) {
  __builtin_amdgcn_global_load_lds((const __attribute__((address_space(1))) void*)g,
                                   (__attribute__((address_space(3))) void*)l, 16, 0, 0);
}

// ---------------- fp32 -> bf16 bulk cast (X pre-cast so GEMM A staging can use DMA) ---
__global__ __launch_bounds__(256) void cast_bf16(const float* __restrict__ src,
                                                 bf16* __restrict__ dst)
{
  size_t i = ((size_t)blockIdx.x * 256 + threadIdx.x) * 8;
  floatx4 a = *(const floatx4*)(src + i);
  floatx4 b = *(const floatx4*)(src + i + 4);
  bf16x8 v;
  v[0] = (bf16)a[0]; v[1] = (bf16)a[1]; v[2] = (bf16)a[2]; v[3] = (bf16)a[3];
  v[4] = (bf16)b[0]; v[5] = (bf16)b[1]; v[6] = (bf16)b[2]; v[7] = (bf16)b[3];
  *(bf16x8*)(dst + i) = v;
}

// ---------------- weight transpose + cast: WT[n][k] = (bf16)W[k][n] ----------------
__global__ __launch_bounds__(256) void transpose1(const float* __restrict__ src,
                                                  bf16* __restrict__ dst)
{
  __shared__ float tile[64][65];
  const int t = threadIdx.x;
  const int col = t & 63, rw = t >> 6;
  const int bx = blockIdx.x * 64, by = blockIdx.y * 64;
  for (int i = rw; i < 64; i += 4)
    tile[i][col] = src[(size_t)(by + i) * DD + bx + col];
  __syncthreads();
  for (int i = rw; i < 64; i += 4)
    dst[(size_t)(bx + i) * DD + by + col] = (bf16)tile[col][i];
}

// ---------------- GEMM: C[16384][2048] = A x B, B given transposed bf16 (BT[n][k]) ----
// BM=256, BN=128, BK=64, 8 waves (4M x 2N grid, 64x64 output per wave).
// 3-deep LDS ring + counted vmcnt(6): stage tile t+2 while computing t; never drain
// vmcnt to 0 in the main loop (loads stay in flight across raw s_barriers).
// XOR chunk-swizzle applied to per-lane GLOBAL source and to the ds_read side.
// A is bf16. AIDX==0: row-major [row][d]. AIDX==1: QKV layout [b][h][l][f].
// EPI==0: C fp32 row-major. EPI==1: C bf16 scattered to QKV layout.
template<int AIDX, int EPI>
__global__ __launch_bounds__(512) void gemm_bt(const bf16* __restrict__ Ab,
    const bf16* __restrict__ BT, void* __restrict__ Cv)
{
  constexpr int Kd = 2048;
  constexpr int NT = Kd / 64;                 // 32 k-tiles
  __shared__ alignas(16) bf16 As[3][256 * 64];   // 96 KB
  __shared__ alignas(16) bf16 Bs[3][128 * 64];   // 48 KB (144 KB total <= 160)
  const int t = threadIdx.x;
  // XCD-aware swizzle: 1024 wgs, 1024 % 8 == 0 -> simple remap is bijective.
  const int id = blockIdx.y * 16 + blockIdx.x;
  const int swz = (id & 7) * 128 + (id >> 3);
  const int bn = swz & 15, bm = swz >> 4;
  const int wv = t >> 6, ln = t & 63;
  const int q = ln >> 4, i16 = ln & 15;
  const int wm = wv >> 1, wn = wv & 1;        // 4(M) x 2(N) wave grid
  const int rsub = ln >> 3, csub = ln & 7;

  floatx4 acc[4][4] = {};

  // per-thread global source offsets for staging (k-advance added per tile)
  size_t aoff[4], boff[2];
#pragma unroll
  for (int j = 0; j < 4; ++j) {
    int r = (wv * 4 + j) * 8 + rsub;          // 0..255
    int sc = (csub ^ (r & 7)) * 8;            // inverse-swizzled source col
    if (AIDX == 0) {
      aoff[j] = (size_t)(bm * 256 + r) * Kd + sc;
    } else {
      int R = bm * 256 + r;
      int b = R >> 11, l = R & 2047;
      aoff[j] = ((size_t)b * NHH * LL + l) * HDD + sc;   // h added as kt*LL*HDD
    }
  }
#pragma unroll
  for (int j = 0; j < 2; ++j) {
    int r = (wv * 2 + j) * 8 + rsub;          // 0..127
    int sc = (csub ^ (r & 7)) * 8;
    boff[j] = (size_t)(bn * 128 + r) * Kd + sc;
  }

  auto STAGE = [&](int bi, int kt) {
    char* abase = (char*)&As[bi][0] + wv * 4096;
    char* bbase = (char*)&Bs[bi][0] + wv * 2048;
#pragma unroll
    for (int j = 0; j < 4; ++j) {
      const bf16* ga = (AIDX == 0) ? (Ab + aoff[j] + kt * 64)
                                   : (Ab + aoff[j] + (size_t)kt * (LL * HDD));
      gl_lds16(ga, abase + j * 1024);
    }
#pragma unroll
    for (int j = 0; j < 2; ++j)
      gl_lds16(BT + boff[j] + kt * 64, bbase + j * 1024);
  };

  STAGE(0, 0);
  STAGE(1, 1);
  asm volatile("s_waitcnt vmcnt(6)\n\ts_barrier" ::: "memory");

  int cur = 0;
  for (int kt = 0; kt < NT; ++kt) {
    int nxt = cur + 2; if (nxt >= 3) nxt -= 3;
    int pf = kt + 2; if (pf >= NT) pf -= NT;   // tail: stages valid-but-unused data
    STAGE(nxt, pf);
#pragma unroll
    for (int kk = 0; kk < 2; ++kk) {
      bf16x8 af[4], bfr[4];
#pragma unroll
      for (int mt = 0; mt < 4; ++mt) {
        int r = wm * 64 + mt * 16 + i16;
        int ch = ((kk * 4 + q) ^ (r & 7)) * 8;
        af[mt] = *(const bf16x8*)&As[cur][r * 64 + ch];
      }
#pragma unroll
      for (int nt = 0; nt < 4; ++nt) {
        int r = wn * 64 + nt * 16 + i16;
        int ch = ((kk * 4 + q) ^ (r & 7)) * 8;
        bfr[nt] = *(const bf16x8*)&Bs[cur][r * 64 + ch];
      }
#pragma unroll
      for (int mt = 0; mt < 4; ++mt)
#pragma unroll
        for (int nt = 0; nt < 4; ++nt)
          acc[mt][nt] = MFMA16(af[mt], bfr[nt], acc[mt][nt]);
    }
    asm volatile("s_waitcnt vmcnt(6)\n\ts_barrier" ::: "memory");
    cur = (cur + 1 == 3) ? 0 : cur + 1;
  }

#pragma unroll
  for (int mt = 0; mt < 4; ++mt)
#pragma unroll
    for (int nt = 0; nt < 4; ++nt)
#pragma unroll
      for (int rg = 0; rg < 4; ++rg) {
        int row = bm * 256 + wm * 64 + mt * 16 + q * 4 + rg;
        int col = bn * 128 + wn * 64 + nt * 16 + i16;
        if (EPI == 0) {
          ((float*)Cv)[(size_t)row * DD + col] = acc[mt][nt][rg];
        } else {
          int b = row >> 11, l = row & 2047;
          int h = col >> 6, f = col & 63;
          ((bf16*)Cv)[((size_t)(b * NHH + h) * LL + l) * HDD + f] = (bf16)acc[mt][nt][rg];
        }
      }
}

// ---------------- RoPE (interleaved pairs), in-place on bf16 Q and K ----------------
__global__ __launch_bounds__(256) void rope_qk(bf16* __restrict__ Q, bf16* __restrict__ Kt)
{
  bf16* X = blockIdx.y ? Kt : Q;
  unsigned p = blockIdx.x * 256u + threadIdx.x;   // pair index < 2^24
  int i = p & 31;
  int l = (p >> 5) & 2047;
  int bh = p >> 16;
  float invf = __expf(-(float)i * 0.28782313662425573f);  // ln(10000)/32
  float th = (float)l * invf;
  float sn, cs;
  __sincosf(th, &sn, &cs);
  size_t off = (size_t)bh * (LL * HDD) + (size_t)l * HDD + 2 * i;
  float x0 = (float)X[off], x1 = (float)X[off + 1];
  X[off]     = (bf16)(x0 * cs - x1 * sn);
  X[off + 1] = (bf16)(x1 * cs + x0 * sn);
}

// ---------------- TTT scan (MFMA version): one block per (b,h), 128 sequential chunks --
__global__ __launch_bounds__(256) void ttt_scan(
    const bf16* Q, const bf16* __restrict__ Kx,
    const bf16* __restrict__ V, const float* __restrict__ W1g,
    const float* __restrict__ b1g, const float* __restrict__ gw,
    const float* __restrict__ gb, bf16* O)
{
  const int bh = blockIdx.x, h = bh & 31;
  const int t = threadIdx.x;
  const int wave = t >> 6, lane = t & 63;
  const int q = lane >> 4, i16 = lane & 15;
  const int kr = t >> 4, sr = t & 15, f0 = sr * 4;   // LN mapping: row kr, cols f0..f0+3

  __shared__ alignas(16) bf16 W1Th[64 * 72];   // [g][f] pitch 72 (144B)
  __shared__ alignas(16) bf16 W1Tl[64 * 72];
  __shared__ alignas(16) bf16 xqs[2][16 * 72]; // chunk bufs, natural [k][f] pitch 72
  __shared__ alignas(16) bf16 xks[2][16 * 72];
  __shared__ alignas(16) bf16 xvs[2][16 * 72];
  __shared__ alignas(16) bf16 xkTs[64 * 24];   // [f][k] = -(1/16)*xk[k][f], pitch 24 (48B)
  __shared__ alignas(16) bf16 gTh[64 * 24];    // grad^T hi, [g][k]
  __shared__ alignas(16) bf16 gTl[64 * 24];    // grad^T lo
  __shared__ alignas(16) bf16 Pm[16 * 24];     // P[k][l] = -(attn+1)*eta_k (tril), pitch 24
  __shared__ alignas(16) float Z1s[16 * 68];   // fp32 Z1 / Z1bar roundtrip, pitch 68 (272B)

  // ---- init state ----
  floatx4 accW[4];                             // W1[16mt+4q+r][16w+i16]
  const float* Wg = W1g + (size_t)h * 4096;
  for (int mt = 0; mt < 4; ++mt)
    for (int r = 0; r < 4; ++r)
      accW[mt][r] = Wg[(16 * mt + 4 * q + r) * 64 + 16 * wave + i16];
  float b1r = b1g[h * 64 + 16 * wave + i16];   // per-lane b1 for col g=16w+i16

  for (int mt = 0; mt < 4; ++mt) {             // initial W1T hi/lo
    bf16x4 h4, l4;
    for (int r = 0; r < 4; ++r) {
      float w = accW[mt][r];
      bf16 hi = (bf16)w;
      h4[r] = hi; l4[r] = (bf16)(w - (float)hi);
    }
    int base = (16 * wave + i16) * 72 + 16 * mt + 4 * q;
    *(bf16x4*)&W1Th[base] = h4;
    *(bf16x4*)&W1Tl[base] = l4;
  }

  float gq[4], bq[4];                          // LN gamma/beta for cols f0..f0+3
  for (int j = 0; j < 4; ++j) {
    gq[j] = gw[h * 64 + f0 + j];
    bq[j] = gb[h * 64 + f0 + j];
  }
  float etar[4];                               // 1/(krow+1), krow = 4q+r (used by wave0)
  for (int r = 0; r < 4; ++r) etar[r] = 1.0f / (float)(4 * q + r + 1);

  const size_t qbase = (size_t)bh * (LL * HDD);
  // prefetch chunk 0 into regs
  bf16x4 rq = *(const bf16x4*)(Q  + qbase + kr * 64 + f0);
  bf16x4 rk = *(const bf16x4*)(Kx + qbase + kr * 64 + f0);
  bf16x4 rv = *(const bf16x4*)(V  + qbase + kr * 64 + f0);

  for (int c = 0; c < 128; ++c) {
    const int pb = c & 1;
    // ---- phase 0: stage chunk from regs into LDS ----
    *(bf16x4*)&xqs[pb][kr * 72 + f0] = rq;
    *(bf16x4*)&xks[pb][kr * 72 + f0] = rk;
    *(bf16x4*)&xvs[pb][kr * 72 + f0] = rv;
    for (int j = 0; j < 4; ++j)
      xkTs[(f0 + j) * 24 + kr] = (bf16)((float)rk[j] * -0.0625f);  // exact pow2 scale
    __syncthreads();   // barrier A

    // ---- stage 1: Z1 = xk @ W1 + b1 (all waves); attn -> P (wave 0) ----
    bf16x8 akf[2], whi[2], wlo[2];
    akf[0] = *(const bf16x8*)&xks[pb][i16 * 72 + q * 8];
    akf[1] = *(const bf16x8*)&xks[pb][i16 * 72 + 32 + q * 8];
    {
      int wb = (16 * wave + i16) * 72 + q * 8;
      whi[0] = *(const bf16x8*)&W1Th[wb];
      whi[1] = *(const bf16x8*)&W1Th[wb + 32];
      wlo[0] = *(const bf16x8*)&W1Tl[wb];
      wlo[1] = *(const bf16x8*)&W1Tl[wb + 32];
    }
    {
      floatx4 z = {b1r, b1r, b1r, b1r};
      z = MFMA16(akf[0], whi[0], z);
      z = MFMA16(akf[1], whi[1], z);
      z = MFMA16(akf[0], wlo[0], z);
      z = MFMA16(akf[1], wlo[1], z);
      for (int r = 0; r < 4; ++r)
        Z1s[(4 * q + r) * 68 + 16 * wave + i16] = z[r];
    }
    if (wave == 0) {
      bf16x8 aq0 = *(const bf16x8*)&xqs[pb][i16 * 72 + q * 8];
      bf16x8 aq1 = *(const bf16x8*)&xqs[pb][i16 * 72 + 32 + q * 8];
      floatx4 at = {};
      at = MFMA16(aq0, akf[0], at);
      at = MFMA16(aq1, akf[1], at);
      for (int r = 0; r < 4; ++r) {
        int krow = 4 * q + r;
        float pv = (i16 <= krow) ? -(at[r] + 1.0f) * etar[r] : 0.0f;
        Pm[krow * 24 + i16] = (bf16)pv;
      }
    }
    __syncthreads();   // barrier B

    // ---- stage B: LN fused-l2 backward -> grad^T hi/lo ----
    {
      floatx4 z4 = *(const floatx4*)&Z1s[kr * 68 + f0];
      float tg[4], sum = 0.f, ssq = 0.f;
      for (int j = 0; j < 4; ++j) {
        tg[j] = (float)rv[j] - (float)rk[j];   // regs still hold chunk c
        sum += z4[j]; ssq += z4[j] * z4[j];
      }
      for (int m = 1; m < 16; m <<= 1) { sum += __shfl_xor(sum, m, 64); ssq += __shfl_xor(ssq, m, 64); }
      float mu = sum * (1.f / 64.f);
      float var = ssq * (1.f / 64.f) - mu * mu;
      float rstd = rsqrtf(var + 1e-6f);
      float xh[4], gx[4], s1 = 0.f, s2 = 0.f;
      for (int j = 0; j < 4; ++j) {
        xh[j] = (z4[j] - mu) * rstd;
        float go = gq[j] * xh[j] + bq[j] - tg[j];
        gx[j] = go * gq[j];
        s1 += gx[j]; s2 += gx[j] * xh[j];
      }
      for (int m = 1; m < 16; m <<= 1) { s1 += __shfl_xor(s1, m, 64); s2 += __shfl_xor(s2, m, 64); }
      for (int j = 0; j < 4; ++j) {
        float gr = (64.f * gx[j] - s1 - xh[j] * s2) * (rstd * (1.f / 64.f));
        bf16 hi = (bf16)gr;
        gTh[(f0 + j) * 24 + kr] = hi;
        gTl[(f0 + j) * 24 + kr] = (bf16)(gr - (float)hi);
      }
    }
    __syncthreads();   // barrier C

    // prefetch chunk c+1 (c=127 reads spill harmlessly into adjacent ws buffers)
    {
      const size_t cb = qbase + (size_t)(c + 1) * 1024 + kr * 64 + f0;
      rq = *(const bf16x4*)(Q  + cb);
      rk = *(const bf16x4*)(Kx + cb);
      rv = *(const bf16x4*)(V  + cb);
    }

    // ---- stage C: Z1_bar = xq@W1 + P@grad + b1 ----
    {
      bf16x8 aq0 = *(const bf16x8*)&xqs[pb][i16 * 72 + q * 8];
      bf16x8 aq1 = *(const bf16x8*)&xqs[pb][i16 * 72 + 32 + q * 8];
      bf16x8 pf  = *(const bf16x8*)&Pm[i16 * 24 + (q & 1) * 8];
      const bf16* gT = (q < 2) ? gTh : gTl;    // K=32 packing: hi halves then lo halves
      bf16x8 bgp = *(const bf16x8*)&gT[(16 * wave + i16) * 24 + (q & 1) * 8];
      floatx4 zb = {b1r, b1r, b1r, b1r};
      zb = MFMA16(aq0, whi[0], zb);
      zb = MFMA16(aq1, whi[1], zb);
      zb = MFMA16(aq0, wlo[0], zb);
      zb = MFMA16(aq1, wlo[1], zb);
      zb = MFMA16(pf, bgp, zb);                // sums P*(grad_hi+grad_lo)
      for (int r = 0; r < 4; ++r)
        Z1s[(4 * q + r) * 68 + 16 * wave + i16] = zb[r];

      // ---- stage D: W1 += -(1/16) xk^T (grad_hi+grad_lo) ; write new W1T; b1 update --
      for (int mt = 0; mt < 4; ++mt) {
        bf16x8 axk = *(const bf16x8*)&xkTs[(16 * mt + i16) * 24 + (q & 1) * 8];
        accW[mt] = MFMA16(axk, bgp, accW[mt]);
      }
      for (int mt = 0; mt < 4; ++mt) {
        bf16x4 h4, l4;
        for (int r = 0; r < 4; ++r) {
          float w = accW[mt][r];
          bf16 hi = (bf16)w;
          h4[r] = hi; l4[r] = (bf16)(w - (float)hi);
        }
        int base = (16 * wave + i16) * 72 + 16 * mt + 4 * q;
        *(bf16x4*)&W1Th[base] = h4;
        *(bf16x4*)&W1Tl[base] = l4;
      }
      {
        const bf16* rh = &gTh[(16 * wave + i16) * 24];
        const bf16* rl = &gTl[(16 * wave + i16) * 24];
        bf16x8 a0 = *(const bf16x8*)rh, a1 = *(const bf16x8*)(rh + 8);
        bf16x8 a2 = *(const bf16x8*)rl, a3 = *(const bf16x8*)(rl + 8);
        float s = 0.f;
        for (int j = 0; j < 8; ++j)
          s += (float)a0[j] + (float)a1[j] + (float)a2[j] + (float)a3[j];
        b1r -= 0.0625f * s;
      }
    }
    __syncthreads();   // barrier D

    // ---- stage E: out = xq + LN_fwd(Z1_bar) -> O (aliases Q) ----
    {
      floatx4 z4 = *(const floatx4*)&Z1s[kr * 68 + f0];
      float sum = 0.f, ssq = 0.f;
      for (int j = 0; j < 4; ++j) { sum += z4[j]; ssq += z4[j] * z4[j]; }
      for (int m = 1; m < 16; m <<= 1) { sum += __shfl_xor(sum, m, 64); ssq += __shfl_xor(ssq, m, 64); }
      float mu = sum * (1.f / 64.f);
      float var = ssq * (1.f / 64.f) - mu * mu;
      float rstd = rsqrtf(var + 1e-6f);
      bf16x4 xq4 = *(const bf16x4*)&xqs[pb][kr * 72 + f0];
      bf16x4 o4;
      for (int j = 0; j < 4; ++j)
        o4[j] = (bf16)((float)xq4[j] + gq[j] * ((z4[j] - mu) * rstd) + bq[j]);
      *(bf16x4*)(O + qbase + (size_t)c * 1024 + kr * 64 + f0) = o4;
    }
    // no barrier here: next phase-0 writes the other chunk buffer; all other
    // producer/consumer pairs are separated by barriers A-D of the next iteration.
  }
}

extern "C" void kernel_launch(void* const* d_in, const int* in_sizes, int n_in,
                              void* d_out, int out_size, void* d_ws, size_t ws_size,
                              hipStream_t stream)
{
  const float* X  = (const float*)d_in[0];
  const float* wq = (const float*)d_in[1];
  const float* wk = (const float*)d_in[2];
  const float* wv = (const float*)d_in[3];
  const float* wo = (const float*)d_in[4];
  const float* W1 = (const float*)d_in[5];
  const float* b1 = (const float*)d_in[6];
  const float* gw = (const float*)d_in[7];
  const float* gb = (const float*)d_in[8];

  bf16* ws = (bf16*)d_ws;
  const size_t NEl = (size_t)BB * LL * DD;   // 33,554,432 elems per tensor
  bf16* Qb = ws;                 // also the scan output O (aliased)
  bf16* Kb = ws + NEl;
  bf16* WT = ws + 2 * NEl;       // single 2048x2048 transposed bf16 weight slot, reused
  bf16* Vb = (bf16*)d_out;       // V bf16 (64 MB) in d_out's first half (d_out = 128 MB fp32)
  bf16* Xb = (bf16*)d_out + NEl; // X bf16 (64 MB) in d_out's second half; both are fully
                                 // consumed before the final GEMM overwrites d_out.
  // workspace: 2*64MB + 8MB = 136,314,880 bytes

  cast_bf16<<<dim3(16384), 256, 0, stream>>>(X, Xb);
  transpose1<<<dim3(32, 32), 256, 0, stream>>>(wq, WT);
  gemm_bt<0, 1><<<dim3(16, 64), 512, 0, stream>>>(Xb, WT, Qb);
  transpose1<<<dim3(32, 32), 256, 0, stream>>>(wk, WT);
  gemm_bt<0, 1><<<dim3(16, 64), 512, 0, stream>>>(Xb, WT, Kb);
  transpose1<<<dim3(32, 32), 256, 0, stream>>>(wv, WT);
  gemm_bt<0, 1><<<dim3(16, 64), 512, 0, stream>>>(Xb, WT, Vb);
  rope_qk<<<dim3(65536, 2), 256, 0, stream>>>(Qb, Kb);
  ttt_scan<<<dim3(256), 256, 0, stream>>>(Qb, Kb, Vb, W1, b1, gw, gb, Qb);
  transpose1<<<dim3(32, 32), 256, 0, stream>>>(wo, WT);
  gemm_bt<1, 0><<<dim3(16, 64), 512, 0, stream>>>(Qb, WT, d_out);
}

// Round 4
// 1230.099 us; speedup vs baseline: 1.0673x; 1.0673x over previous
//
#include <hip/hip_runtime.h>

typedef __bf16 bf16;
typedef __bf16 bf16x4 __attribute__((ext_vector_type(4)));
typedef __bf16 bf16x8 __attribute__((ext_vector_type(8)));
typedef float floatx4 __attribute__((ext_vector_type(4)));

#define BB 8
#define LL 2048
#define DD 2048
#define NHH 32
#define HDD 64

#define MFMA16(a, b, c) __builtin_amdgcn_mfma_f32_16x16x32_bf16(a, b, c, 0, 0, 0)

// async global->LDS DMA, 16B per lane; dest = wave-uniform base + lane*16
__device__ __forceinline__ void gl_lds16(const void* g, void* l) {
  __builtin_amdgcn_global_load_lds((const __attribute__((address_space(1))) void*)g,
                                   (__attribute__((address_space(3))) void*)l, 16, 0, 0);
}

// ---------------- fp32 -> bf16 bulk cast (X pre-cast so GEMM A staging can use DMA) ---
__global__ __launch_bounds__(256) void cast_bf16(const float* __restrict__ src,
                                                 bf16* __restrict__ dst)
{
  size_t i = ((size_t)blockIdx.x * 256 + threadIdx.x) * 8;
  floatx4 a = *(const floatx4*)(src + i);
  floatx4 b = *(const floatx4*)(src + i + 4);
  bf16x8 v;
  v[0] = (bf16)a[0]; v[1] = (bf16)a[1]; v[2] = (bf16)a[2]; v[3] = (bf16)a[3];
  v[4] = (bf16)b[0]; v[5] = (bf16)b[1]; v[6] = (bf16)b[2]; v[7] = (bf16)b[3];
  *(bf16x8*)(dst + i) = v;
}

// ---------------- weight transpose + cast: WT[n][k] = (bf16)W[k][n] ----------------
__global__ __launch_bounds__(256) void transpose1(const float* __restrict__ src,
                                                  bf16* __restrict__ dst)
{
  __shared__ float tile[64][65];
  const int t = threadIdx.x;
  const int col = t & 63, rw = t >> 6;
  const int bx = blockIdx.x * 64, by = blockIdx.y * 64;
  for (int i = rw; i < 64; i += 4)
    tile[i][col] = src[(size_t)(by + i) * DD + bx + col];
  __syncthreads();
  for (int i = rw; i < 64; i += 4)
    dst[(size_t)(bx + i) * DD + by + col] = (bf16)tile[col][i];
}

// ---------------- GEMM (round-2 known-good): C[16384][2048] = A x B, BT[n][k] bf16 ----
// Staging: global_load_lds dwordx4, linear LDS [128][64], XOR chunk-swizzle
// (chunk ^= row&7) applied to the per-lane GLOBAL source and to the ds_read side.
template<int AIDX, int EPI>
__global__ __launch_bounds__(256) void gemm_bt(const bf16* __restrict__ Ab,
    const bf16* __restrict__ BT, void* __restrict__ Cv)
{
  constexpr int Kd = 2048;
  __shared__ alignas(16) bf16 As[128 * 64];
  __shared__ alignas(16) bf16 Bs[128 * 64];
  const int t = threadIdx.x;
  // XCD-aware swizzle: 2048 wgs, 2048%8==0 -> simple remap is bijective.
  const int id = blockIdx.y * 16 + blockIdx.x;
  const int swz = (id & 7) * 256 + (id >> 3);
  const int bn = swz & 15, bm = swz >> 4;
  const int wave = t >> 6, lane = t & 63;
  const int m16 = lane & 15, quad = lane >> 4;
  floatx4 acc[2][8] = {};
  const int r0 = t >> 3;                 // 0..31: row within 32-row stripe
  const int scc = (t & 7) ^ (r0 & 7);    // inverse-swizzled source 16B-chunk
  const bf16* Bb = BT + (size_t)(bn * 128) * Kd;
  char* AsB = (char*)As + wave * 1024;   // wave-uniform DMA dest bases
  char* BsB = (char*)Bs + wave * 1024;

  for (int k0 = 0; k0 < Kd; k0 += 64) {
    for (int i = 0; i < 4; ++i) {
      int r = r0 + 32 * i;
      int col = k0 + scc * 8;
      const bf16* ga;
      if (AIDX == 0) {
        ga = Ab + (size_t)(bm * 128 + r) * Kd + col;
      } else {
        int R = bm * 128 + r;
        int b = R >> 11, l = R & 2047;
        int h = col >> 6, f = col & 63;
        ga = Ab + (((size_t)(b * NHH + h) * LL + l) * HDD + f);
      }
      gl_lds16(ga, AsB + i * 4096);
      gl_lds16(Bb + (size_t)r * Kd + col, BsB + i * 4096);
    }
    __syncthreads();
    const int sw = m16 & 7;
    for (int kk = 0; kk < 2; ++kk) {
      bf16x8 af[2], bfr[8];
      const int c = ((kk * 4 + quad) ^ sw) * 8;
      for (int mt = 0; mt < 2; ++mt)
        af[mt] = *(const bf16x8*)&As[(wave * 32 + mt * 16 + m16) * 64 + c];
      for (int nt = 0; nt < 8; ++nt)
        bfr[nt] = *(const bf16x8*)&Bs[(nt * 16 + m16) * 64 + c];
      for (int mt = 0; mt < 2; ++mt)
        for (int nt = 0; nt < 8; ++nt)
          acc[mt][nt] = MFMA16(af[mt], bfr[nt], acc[mt][nt]);
    }
    __syncthreads();
  }

  for (int mt = 0; mt < 2; ++mt)
    for (int nt = 0; nt < 8; ++nt)
      for (int rg = 0; rg < 4; ++rg) {
        int row = bm * 128 + wave * 32 + mt * 16 + quad * 4 + rg;
        int col = bn * 128 + nt * 16 + m16;
        if (EPI == 0) {
          ((float*)Cv)[(size_t)row * DD + col] = acc[mt][nt][rg];
        } else {
          int b = row >> 11, l = row & 2047;
          int h = col >> 6, f = col & 63;
          ((bf16*)Cv)[((size_t)(b * NHH + h) * LL + l) * HDD + f] = (bf16)acc[mt][nt][rg];
        }
      }
}

// ---------------- RoPE (interleaved pairs), in-place on bf16 Q and K ----------------
__global__ __launch_bounds__(256) void rope_qk(bf16* __restrict__ Q, bf16* __restrict__ Kt)
{
  bf16* X = blockIdx.y ? Kt : Q;
  unsigned p = blockIdx.x * 256u + threadIdx.x;   // pair index < 2^24
  int i = p & 31;
  int l = (p >> 5) & 2047;
  int bh = p >> 16;
  float invf = __expf(-(float)i * 0.28782313662425573f);  // ln(10000)/32
  float th = (float)l * invf;
  float sn, cs;
  __sincosf(th, &sn, &cs);
  size_t off = (size_t)bh * (LL * HDD) + (size_t)l * HDD + 2 * i;
  float x0 = (float)X[off], x1 = (float)X[off + 1];
  X[off]     = (bf16)(x0 * cs - x1 * sn);
  X[off + 1] = (bf16)(x1 * cs + x0 * sn);
}

// ---------------- TTT scan: 512 threads, 8 waves, role-split ----------------
// Waves 0-3 ("W"): own W1 state (accW fp32, g-slice per wave): Z1=xk@W1 (stage1),
//   LN-bwd grad (stage B), W1 accum MFMA + b1 (stage C), hi/lo repack (stage E slot).
// Waves 4-7 ("Q"): Zq=xq@W1 in parallel with Z1 (stage1, kept in regs), attn->Pm
//   (wave 4), Zbar=Zq+P@grad (stage C), output LN+store (stage E).
// 4 barriers/chunk; 2 waves/SIMD (was 1) hides the serial shfl/LN latency.
// Arithmetic order identical to the 4-wave version (bit-identical results).
__global__ __launch_bounds__(512) void ttt_scan(
    const bf16* Q, const bf16* __restrict__ Kx,
    const bf16* __restrict__ V, const float* __restrict__ W1g,
    const float* __restrict__ b1g, const float* __restrict__ gw,
    const float* __restrict__ gb, bf16* O)
{
  const int bh = blockIdx.x, h = bh & 31;
  const int t = threadIdx.x;
  const int lane = t & 63, wv = t >> 6;
  const int q = lane >> 4, i16 = lane & 15;
  const bool isW = wv < 4;
  const int wg = wv & 3;                       // g-slice index within group
  const int tg = t & 255;                      // index within 256-thread group
  const int kr = tg >> 4, sr = tg & 15, f0 = sr * 4;

  __shared__ alignas(16) bf16 W1Th[64 * 72];   // [g][f] pitch 72
  __shared__ alignas(16) bf16 W1Tl[64 * 72];
  __shared__ alignas(16) bf16 xqs[2][16 * 72];
  __shared__ alignas(16) bf16 xks[2][16 * 72];
  __shared__ alignas(16) bf16 xkTs[64 * 24];   // [f][k] = -(1/16)*xk, pitch 24
  __shared__ alignas(16) bf16 gTh[64 * 24];    // grad^T hi, [g][k]
  __shared__ alignas(16) bf16 gTl[64 * 24];
  __shared__ alignas(16) bf16 Pm[16 * 24];     // P = -(attn+1)*eta (tril)
  __shared__ alignas(16) float Z1s[16 * 68];   // fp32 Z1 / Zbar roundtrip

  // ---- init state ----
  floatx4 accW[4];                             // W-waves only
  const float* Wg = W1g + (size_t)h * 4096;
  float b1r = b1g[h * 64 + 16 * wg + i16];     // per-lane b1 col (both groups)
  if (isW) {
    for (int mt = 0; mt < 4; ++mt)
      for (int r = 0; r < 4; ++r)
        accW[mt][r] = Wg[(16 * mt + 4 * q + r) * 64 + 16 * wg + i16];
    for (int mt = 0; mt < 4; ++mt) {
      bf16x4 h4, l4;
      for (int r = 0; r < 4; ++r) {
        float w = accW[mt][r];
        bf16 hi = (bf16)w;
        h4[r] = hi; l4[r] = (bf16)(w - (float)hi);
      }
      int base = (16 * wg + i16) * 72 + 16 * mt + 4 * q;
      *(bf16x4*)&W1Th[base] = h4;
      *(bf16x4*)&W1Tl[base] = l4;
    }
  }
  float gq4[4], bq4[4];
  for (int j = 0; j < 4; ++j) {
    gq4[j] = gw[h * 64 + f0 + j];
    bq4[j] = gb[h * 64 + f0 + j];
  }
  float etar[4];
  for (int r = 0; r < 4; ++r) etar[r] = 1.0f / (float)(4 * q + r + 1);

  const size_t qbase = (size_t)bh * (LL * HDD);
  bf16x4 rq{}, rk{}, rv{};
  if (isW) {
    rk = *(const bf16x4*)(Kx + qbase + kr * 64 + f0);
    rv = *(const bf16x4*)(V  + qbase + kr * 64 + f0);
  } else {
    rq = *(const bf16x4*)(Q + qbase + kr * 64 + f0);
  }
  floatx4 zq{};                                // Q-waves: xq@W1+b1, stage1 -> stageC

  for (int c = 0; c < 128; ++c) {
    const int pb = c & 1;
    // ---- phase 0: stage chunk from regs into LDS ----
    if (isW) {
      *(bf16x4*)&xks[pb][kr * 72 + f0] = rk;
      for (int j = 0; j < 4; ++j)
        xkTs[(f0 + j) * 24 + kr] = (bf16)((float)rk[j] * -0.0625f);
    } else {
      *(bf16x4*)&xqs[pb][kr * 72 + f0] = rq;
    }
    __syncthreads();   // barrier A

    // ---- stage 1: W: Z1 = xk@W1+b1 -> Z1s ; Q: Zq = xq@W1+b1 (regs), w4: attn->Pm ----
    {
      int wb = (16 * wg + i16) * 72 + q * 8;
      bf16x8 whi0 = *(const bf16x8*)&W1Th[wb];
      bf16x8 whi1 = *(const bf16x8*)&W1Th[wb + 32];
      bf16x8 wlo0 = *(const bf16x8*)&W1Tl[wb];
      bf16x8 wlo1 = *(const bf16x8*)&W1Tl[wb + 32];
      if (isW) {
        bf16x8 ak0 = *(const bf16x8*)&xks[pb][i16 * 72 + q * 8];
        bf16x8 ak1 = *(const bf16x8*)&xks[pb][i16 * 72 + 32 + q * 8];
        floatx4 z = {b1r, b1r, b1r, b1r};
        z = MFMA16(ak0, whi0, z);
        z = MFMA16(ak1, whi1, z);
        z = MFMA16(ak0, wlo0, z);
        z = MFMA16(ak1, wlo1, z);
        for (int r = 0; r < 4; ++r)
          Z1s[(4 * q + r) * 68 + 16 * wg + i16] = z[r];
      } else {
        bf16x8 aq0 = *(const bf16x8*)&xqs[pb][i16 * 72 + q * 8];
        bf16x8 aq1 = *(const bf16x8*)&xqs[pb][i16 * 72 + 32 + q * 8];
        floatx4 z = {b1r, b1r, b1r, b1r};
        z = MFMA16(aq0, whi0, z);
        z = MFMA16(aq1, whi1, z);
        z = MFMA16(aq0, wlo0, z);
        z = MFMA16(aq1, wlo1, z);
        zq = z;
        if (wv == 4) {
          bf16x8 ak0 = *(const bf16x8*)&xks[pb][i16 * 72 + q * 8];
          bf16x8 ak1 = *(const bf16x8*)&xks[pb][i16 * 72 + 32 + q * 8];
          floatx4 at = {};
          at = MFMA16(aq0, ak0, at);
          at = MFMA16(aq1, ak1, at);
          for (int r = 0; r < 4; ++r) {
            int krow = 4 * q + r;
            float pv = (i16 <= krow) ? -(at[r] + 1.0f) * etar[r] : 0.0f;
            Pm[krow * 24 + i16] = (bf16)pv;
          }
        }
      }
    }
    __syncthreads();   // barrier B

    // ---- stage B: W: LN fused-l2 backward -> grad^T hi/lo ; Q: prefetch rq(c+1) ----
    if (isW) {
      floatx4 z4 = *(const floatx4*)&Z1s[kr * 68 + f0];
      float tg4[4], sum = 0.f, ssq = 0.f;
      for (int j = 0; j < 4; ++j) {
        tg4[j] = (float)rv[j] - (float)rk[j];
        sum += z4[j]; ssq += z4[j] * z4[j];
      }
      for (int m = 1; m < 16; m <<= 1) { sum += __shfl_xor(sum, m, 64); ssq += __shfl_xor(ssq, m, 64); }
      float mu = sum * (1.f / 64.f);
      float var = ssq * (1.f / 64.f) - mu * mu;
      float rstd = rsqrtf(var + 1e-6f);
      float xh[4], gx[4], s1 = 0.f, s2 = 0.f;
      for (int j = 0; j < 4; ++j) {
        xh[j] = (z4[j] - mu) * rstd;
        float go = gq4[j] * xh[j] + bq4[j] - tg4[j];
        gx[j] = go * gq4[j];
        s1 += gx[j]; s2 += gx[j] * xh[j];
      }
      for (int m = 1; m < 16; m <<= 1) { s1 += __shfl_xor(s1, m, 64); s2 += __shfl_xor(s2, m, 64); }
      for (int j = 0; j < 4; ++j) {
        float gr = (64.f * gx[j] - s1 - xh[j] * s2) * (rstd * (1.f / 64.f));
        bf16 hi = (bf16)gr;
        gTh[(f0 + j) * 24 + kr] = hi;
        gTl[(f0 + j) * 24 + kr] = (bf16)(gr - (float)hi);
      }
    } else {
      const size_t cb = qbase + (size_t)(c + 1) * 1024 + kr * 64 + f0;
      rq = *(const bf16x4*)(Q + cb);   // c=127 spills into adjacent ws buffer (harmless)
    }
    __syncthreads();   // barrier C

    // ---- stage C: W: accW += -(1/16) xk^T grad, b1 ; Q: Zbar = Zq + P@grad -> Z1s ----
    if (isW) {
      const size_t cb = qbase + (size_t)(c + 1) * 1024 + kr * 64 + f0;
      rk = *(const bf16x4*)(Kx + cb);
      rv = *(const bf16x4*)(V + cb);
      const bf16* gT = (q < 2) ? gTh : gTl;    // K=32 hi/lo packing
      bf16x8 bgp = *(const bf16x8*)&gT[(16 * wg + i16) * 24 + (q & 1) * 8];
      for (int mt = 0; mt < 4; ++mt) {
        bf16x8 axk = *(const bf16x8*)&xkTs[(16 * mt + i16) * 24 + (q & 1) * 8];
        accW[mt] = MFMA16(axk, bgp, accW[mt]);
      }
      const bf16* rh = &gTh[(16 * wg + i16) * 24];
      const bf16* rl = &gTl[(16 * wg + i16) * 24];
      bf16x8 a0 = *(const bf16x8*)rh, a1 = *(const bf16x8*)(rh + 8);
      bf16x8 a2 = *(const bf16x8*)rl, a3 = *(const bf16x8*)(rl + 8);
      float s = 0.f;
      for (int j = 0; j < 8; ++j)
        s += (float)a0[j] + (float)a1[j] + (float)a2[j] + (float)a3[j];
      b1r -= 0.0625f * s;
    } else {
      bf16x8 pf = *(const bf16x8*)&Pm[i16 * 24 + (q & 1) * 8];
      const bf16* gT = (q < 2) ? gTh : gTl;
      bf16x8 bgp = *(const bf16x8*)&gT[(16 * wg + i16) * 24 + (q & 1) * 8];
      floatx4 zb = MFMA16(pf, bgp, zq);
      for (int r = 0; r < 4; ++r)
        Z1s[(4 * q + r) * 68 + 16 * wg + i16] = zb[r];
      const bf16* rh = &gTh[(16 * wg + i16) * 24];
      const bf16* rl = &gTl[(16 * wg + i16) * 24];
      bf16x8 a0 = *(const bf16x8*)rh, a1 = *(const bf16x8*)(rh + 8);
      bf16x8 a2 = *(const bf16x8*)rl, a3 = *(const bf16x8*)(rl + 8);
      float s = 0.f;
      for (int j = 0; j < 8; ++j)
        s += (float)a0[j] + (float)a1[j] + (float)a2[j] + (float)a3[j];
      b1r -= 0.0625f * s;
    }
    __syncthreads();   // barrier D

    // ---- stage E: W: repack W1T hi/lo ; Q: out = xq + LN_fwd(Zbar) -> O ----
    if (isW) {
      for (int mt = 0; mt < 4; ++mt) {
        bf16x4 h4, l4;
        for (int r = 0; r < 4; ++r) {
          float w = accW[mt][r];
          bf16 hi = (bf16)w;
          h4[r] = hi; l4[r] = (bf16)(w - (float)hi);
        }
        int base = (16 * wg + i16) * 72 + 16 * mt + 4 * q;
        *(bf16x4*)&W1Th[base] = h4;
        *(bf16x4*)&W1Tl[base] = l4;
      }
    } else {
      floatx4 z4 = *(const floatx4*)&Z1s[kr * 68 + f0];
      float sum = 0.f, ssq = 0.f;
      for (int j = 0; j < 4; ++j) { sum += z4[j]; ssq += z4[j] * z4[j]; }
      for (int m = 1; m < 16; m <<= 1) { sum += __shfl_xor(sum, m, 64); ssq += __shfl_xor(ssq, m, 64); }
      float mu = sum * (1.f / 64.f);
      float var = ssq * (1.f / 64.f) - mu * mu;
      float rstd = rsqrtf(var + 1e-6f);
      bf16x4 xq4 = *(const bf16x4*)&xqs[pb][kr * 72 + f0];
      bf16x4 o4;
      for (int j = 0; j < 4; ++j)
        o4[j] = (bf16)((float)xq4[j] + gq4[j] * ((z4[j] - mu) * rstd) + bq4[j]);
      *(bf16x4*)(O + qbase + (size_t)c * 1024 + kr * 64 + f0) = o4;
    }
    // no barrier: next phase-0 writes the other chunk buffer; all other
    // producer/consumer pairs are separated by barrier A of the next iteration.
  }
}

extern "C" void kernel_launch(void* const* d_in, const int* in_sizes, int n_in,
                              void* d_out, int out_size, void* d_ws, size_t ws_size,
                              hipStream_t stream)
{
  const float* X  = (const float*)d_in[0];
  const float* wq = (const float*)d_in[1];
  const float* wk = (const float*)d_in[2];
  const float* wv = (const float*)d_in[3];
  const float* wo = (const float*)d_in[4];
  const float* W1 = (const float*)d_in[5];
  const float* b1 = (const float*)d_in[6];
  const float* gw = (const float*)d_in[7];
  const float* gb = (const float*)d_in[8];

  bf16* ws = (bf16*)d_ws;
  const size_t NEl = (size_t)BB * LL * DD;   // 33,554,432 elems per tensor
  bf16* Qb = ws;                 // also the scan output O (aliased)
  bf16* Kb = ws + NEl;
  bf16* WT = ws + 2 * NEl;       // single 2048x2048 transposed bf16 weight slot, reused
  bf16* Vb = (bf16*)d_out;       // V bf16 (64 MB) in d_out's first half (d_out = 128 MB fp32)
  bf16* Xb = (bf16*)d_out + NEl; // X bf16 (64 MB) in d_out's second half; both are fully
                                 // consumed before the final GEMM overwrites d_out.

  cast_bf16<<<dim3(16384), 256, 0, stream>>>(X, Xb);
  transpose1<<<dim3(32, 32), 256, 0, stream>>>(wq, WT);
  gemm_bt<0, 1><<<dim3(16, 128), 256, 0, stream>>>(Xb, WT, Qb);
  transpose1<<<dim3(32, 32), 256, 0, stream>>>(wk, WT);
  gemm_bt<0, 1><<<dim3(16, 128), 256, 0, stream>>>(Xb, WT, Kb);
  transpose1<<<dim3(32, 32), 256, 0, stream>>>(wv, WT);
  gemm_bt<0, 1><<<dim3(16, 128), 256, 0, stream>>>(Xb, WT, Vb);
  rope_qk<<<dim3(65536, 2), 256, 0, stream>>>(Qb, Kb);
  ttt_scan<<<dim3(256), 512, 0, stream>>>(Qb, Kb, Vb, W1, b1, gw, gb, Qb);
  transpose1<<<dim3(32, 32), 256, 0, stream>>>(wo, WT);
  gemm_bt<1, 0><<<dim3(16, 128), 256, 0, stream>>>(Qb, WT, d_out);
}

// Round 5
// 1195.869 us; speedup vs baseline: 1.0979x; 1.0286x over previous
//
#include <hip/hip_runtime.h>

typedef __bf16 bf16;
typedef __bf16 bf16x4 __attribute__((ext_vector_type(4)));
typedef __bf16 bf16x8 __attribute__((ext_vector_type(8)));
typedef float floatx4 __attribute__((ext_vector_type(4)));

#define BB 8
#define LL 2048
#define DD 2048
#define NHH 32
#define HDD 64

#define MFMA16(a, b, c) __builtin_amdgcn_mfma_f32_16x16x32_bf16(a, b, c, 0, 0, 0)

// async global->LDS DMA, 16B per lane; dest = wave-uniform base + lane*16
__device__ __forceinline__ void gl_lds16(const void* g, void* l) {
  __builtin_amdgcn_global_load_lds((const __attribute__((address_space(1))) void*)g,
                                   (__attribute__((address_space(3))) void*)l, 16, 0, 0);
}

__device__ __forceinline__ unsigned bfbits(bf16 x) {
  union { bf16 b; unsigned short u; } c; c.b = x; return (unsigned)c.u;
}

// ---------------- fp32 -> bf16 bulk cast (X pre-cast so GEMM A staging can use DMA) ---
__global__ __launch_bounds__(256) void cast_bf16(const float* __restrict__ src,
                                                 bf16* __restrict__ dst)
{
  size_t i = ((size_t)blockIdx.x * 256 + threadIdx.x) * 8;
  floatx4 a = *(const floatx4*)(src + i);
  floatx4 b = *(const floatx4*)(src + i + 4);
  bf16x8 v;
  v[0] = (bf16)a[0]; v[1] = (bf16)a[1]; v[2] = (bf16)a[2]; v[3] = (bf16)a[3];
  v[4] = (bf16)b[0]; v[5] = (bf16)b[1]; v[6] = (bf16)b[2]; v[7] = (bf16)b[3];
  *(bf16x8*)(dst + i) = v;
}

// ---------------- weight transpose + cast: WT[n][k] = (bf16)W[k][n] ----------------
__global__ __launch_bounds__(256) void transpose1(const float* __restrict__ src,
                                                  bf16* __restrict__ dst)
{
  __shared__ float tile[64][65];
  const int t = threadIdx.x;
  const int col = t & 63, rw = t >> 6;
  const int bx = blockIdx.x * 64, by = blockIdx.y * 64;
  for (int i = rw; i < 64; i += 4)
    tile[i][col] = src[(size_t)(by + i) * DD + bx + col];
  __syncthreads();
  for (int i = rw; i < 64; i += 4)
    dst[(size_t)(bx + i) * DD + by + col] = (bf16)tile[col][i];
}

// ---------------- GEMM (round-2 known-good): C[16384][2048] = A x B, BT[n][k] bf16 ----
// Staging: global_load_lds dwordx4, linear LDS [128][64], XOR chunk-swizzle
// (chunk ^= row&7) applied to the per-lane GLOBAL source and to the ds_read side.
// RP==1: fuse RoPE into the epilogue (pairs are adjacent lanes; rotate fp32 acc
// before the bf16 store — replaces the separate rope_qk pass).
template<int AIDX, int EPI, int RP>
__global__ __launch_bounds__(256) void gemm_bt(const bf16* __restrict__ Ab,
    const bf16* __restrict__ BT, void* __restrict__ Cv)
{
  constexpr int Kd = 2048;
  __shared__ alignas(16) bf16 As[128 * 64];
  __shared__ alignas(16) bf16 Bs[128 * 64];
  const int t = threadIdx.x;
  // XCD-aware swizzle: 2048 wgs, 2048%8==0 -> simple remap is bijective.
  const int id = blockIdx.y * 16 + blockIdx.x;
  const int swz = (id & 7) * 256 + (id >> 3);
  const int bn = swz & 15, bm = swz >> 4;
  const int wave = t >> 6, lane = t & 63;
  const int m16 = lane & 15, quad = lane >> 4;
  floatx4 acc[2][8] = {};
  const int r0 = t >> 3;                 // 0..31: row within 32-row stripe
  const int scc = (t & 7) ^ (r0 & 7);    // inverse-swizzled source 16B-chunk
  const bf16* Bb = BT + (size_t)(bn * 128) * Kd;
  char* AsB = (char*)As + wave * 1024;   // wave-uniform DMA dest bases
  char* BsB = (char*)Bs + wave * 1024;

  for (int k0 = 0; k0 < Kd; k0 += 64) {
    for (int i = 0; i < 4; ++i) {
      int r = r0 + 32 * i;
      int col = k0 + scc * 8;
      const bf16* ga;
      if (AIDX == 0) {
        ga = Ab + (size_t)(bm * 128 + r) * Kd + col;
      } else {
        int R = bm * 128 + r;
        int b = R >> 11, l = R & 2047;
        int h = col >> 6, f = col & 63;
        ga = Ab + (((size_t)(b * NHH + h) * LL + l) * HDD + f);
      }
      gl_lds16(ga, AsB + i * 4096);
      gl_lds16(Bb + (size_t)r * Kd + col, BsB + i * 4096);
    }
    __syncthreads();
    const int sw = m16 & 7;
    for (int kk = 0; kk < 2; ++kk) {
      bf16x8 af[2], bfr[8];
      const int c = ((kk * 4 + quad) ^ sw) * 8;
      for (int mt = 0; mt < 2; ++mt)
        af[mt] = *(const bf16x8*)&As[(wave * 32 + mt * 16 + m16) * 64 + c];
      for (int nt = 0; nt < 8; ++nt)
        bfr[nt] = *(const bf16x8*)&Bs[(nt * 16 + m16) * 64 + c];
      for (int mt = 0; mt < 2; ++mt)
        for (int nt = 0; nt < 8; ++nt)
          acc[mt][nt] = MFMA16(af[mt], bfr[nt], acc[mt][nt]);
    }
    __syncthreads();
  }

  float invf[8];
  if (RP) {
#pragma unroll
    for (int nt = 0; nt < 8; ++nt) {
      int col = bn * 128 + nt * 16 + m16;
      int i = (col >> 1) & 31;
      invf[nt] = __expf(-(float)i * 0.28782313662425573f);  // ln(10000)/32
    }
  }

  for (int mt = 0; mt < 2; ++mt)
    for (int nt = 0; nt < 8; ++nt)
      for (int rg = 0; rg < 4; ++rg) {
        int row = bm * 128 + wave * 32 + mt * 16 + quad * 4 + rg;
        int col = bn * 128 + nt * 16 + m16;
        float v = acc[mt][nt][rg];
        if (RP) {
          float o = __shfl_xor(v, 1, 64);        // partner feature of the pair
          float sn, cs;
          __sincosf((float)(row & 2047) * invf[nt], &sn, &cs);
          v = (m16 & 1) ? (v * cs + o * sn) : (v * cs - o * sn);
        }
        if (EPI == 0) {
          ((float*)Cv)[(size_t)row * DD + col] = v;
        } else {
          int b = row >> 11, l = row & 2047;
          int h = col >> 6, f = col & 63;
          ((bf16*)Cv)[((size_t)(b * NHH + h) * LL + l) * HDD + f] = (bf16)v;
        }
      }
}

// ---------------- TTT scan (4-wave MFMA, round-2 structure + paired LDS writes) -------
// Transposed scatter stores (xkTs, gTh, gTl) previously put 16 lanes into 2 banks
// (row stride 48B = 16 dwords mod 32). Fix: adjacent-kr lanes pair via shfl_xor(.,16);
// even-kr lanes write full dwords (own | partner<<16) -> half the stores, no same-dword
// serialization. Stored bits identical; readers unchanged.
__global__ __launch_bounds__(256) void ttt_scan(
    const bf16* Q, const bf16* __restrict__ Kx,
    const bf16* __restrict__ V, const float* __restrict__ W1g,
    const float* __restrict__ b1g, const float* __restrict__ gw,
    const float* __restrict__ gb, bf16* O)
{
  const int bh = blockIdx.x, h = bh & 31;
  const int t = threadIdx.x;
  const int wave = t >> 6, lane = t & 63;
  const int q = lane >> 4, i16 = lane & 15;
  const int kr = t >> 4, sr = t & 15, f0 = sr * 4;   // LN mapping: row kr, cols f0..f0+3

  __shared__ alignas(16) bf16 W1Th[64 * 72];   // [g][f] pitch 72 (144B)
  __shared__ alignas(16) bf16 W1Tl[64 * 72];
  __shared__ alignas(16) bf16 xqs[2][16 * 72]; // chunk bufs, natural [k][f] pitch 72
  __shared__ alignas(16) bf16 xks[2][16 * 72];
  __shared__ alignas(16) bf16 xkTs[64 * 24];   // [f][k] = -(1/16)*xk[k][f], pitch 24 (48B)
  __shared__ alignas(16) bf16 gTh[64 * 24];    // grad^T hi, [g][k]
  __shared__ alignas(16) bf16 gTl[64 * 24];    // grad^T lo
  __shared__ alignas(16) bf16 Pm[16 * 24];     // P[k][l] = -(attn+1)*eta_k (tril), pitch 24
  __shared__ alignas(16) float Z1s[16 * 68];   // fp32 Z1 / Z1bar roundtrip, pitch 68 (272B)

  // ---- init state ----
  floatx4 accW[4];                             // W1[16mt+4q+r][16w+i16]
  const float* Wg = W1g + (size_t)h * 4096;
  for (int mt = 0; mt < 4; ++mt)
    for (int r = 0; r < 4; ++r)
      accW[mt][r] = Wg[(16 * mt + 4 * q + r) * 64 + 16 * wave + i16];
  float b1r = b1g[h * 64 + 16 * wave + i16];   // per-lane b1 for col g=16w+i16

  for (int mt = 0; mt < 4; ++mt) {             // initial W1T hi/lo
    bf16x4 h4, l4;
    for (int r = 0; r < 4; ++r) {
      float w = accW[mt][r];
      bf16 hi = (bf16)w;
      h4[r] = hi; l4[r] = (bf16)(w - (float)hi);
    }
    int base = (16 * wave + i16) * 72 + 16 * mt + 4 * q;
    *(bf16x4*)&W1Th[base] = h4;
    *(bf16x4*)&W1Tl[base] = l4;
  }

  float gq[4], bq[4];                          // LN gamma/beta for cols f0..f0+3
  for (int j = 0; j < 4; ++j) {
    gq[j] = gw[h * 64 + f0 + j];
    bq[j] = gb[h * 64 + f0 + j];
  }
  float etar[4];                               // 1/(krow+1), krow = 4q+r (used by wave0)
  for (int r = 0; r < 4; ++r) etar[r] = 1.0f / (float)(4 * q + r + 1);

  const size_t qbase = (size_t)bh * (LL * HDD);
  // prefetch chunk 0 into regs
  bf16x4 rq = *(const bf16x4*)(Q  + qbase + kr * 64 + f0);
  bf16x4 rk = *(const bf16x4*)(Kx + qbase + kr * 64 + f0);
  bf16x4 rv = *(const bf16x4*)(V  + qbase + kr * 64 + f0);

  for (int c = 0; c < 128; ++c) {
    const int pb = c & 1;
    // ---- phase 0: stage chunk from regs into LDS (paired xkT writes) ----
    *(bf16x4*)&xqs[pb][kr * 72 + f0] = rq;
    *(bf16x4*)&xks[pb][kr * 72 + f0] = rk;
    {
      bf16 s0 = (bf16)((float)rk[0] * -0.0625f), s1 = (bf16)((float)rk[1] * -0.0625f);
      bf16 s2 = (bf16)((float)rk[2] * -0.0625f), s3 = (bf16)((float)rk[3] * -0.0625f);
      unsigned p0 = bfbits(s0) | (bfbits(s1) << 16);
      unsigned p1 = bfbits(s2) | (bfbits(s3) << 16);
      unsigned q0 = (unsigned)__shfl_xor((int)p0, 16, 64);
      unsigned q1 = (unsigned)__shfl_xor((int)p1, 16, 64);
      if (!(kr & 1)) {
        *(unsigned*)&xkTs[(f0 + 0) * 24 + kr] = (p0 & 0xffffu) | (q0 << 16);
        *(unsigned*)&xkTs[(f0 + 1) * 24 + kr] = (p0 >> 16) | (q0 & 0xffff0000u);
        *(unsigned*)&xkTs[(f0 + 2) * 24 + kr] = (p1 & 0xffffu) | (q1 << 16);
        *(unsigned*)&xkTs[(f0 + 3) * 24 + kr] = (p1 >> 16) | (q1 & 0xffff0000u);
      }
    }
    __syncthreads();   // barrier A

    // ---- stage 1: Z1 = xk @ W1 + b1 (all waves); attn -> P (wave 0) ----
    bf16x8 akf[2], whi[2], wlo[2];
    akf[0] = *(const bf16x8*)&xks[pb][i16 * 72 + q * 8];
    akf[1] = *(const bf16x8*)&xks[pb][i16 * 72 + 32 + q * 8];
    {
      int wb = (16 * wave + i16) * 72 + q * 8;
      whi[0] = *(const bf16x8*)&W1Th[wb];
      whi[1] = *(const bf16x8*)&W1Th[wb + 32];
      wlo[0] = *(const bf16x8*)&W1Tl[wb];
      wlo[1] = *(const bf16x8*)&W1Tl[wb + 32];
    }
    {
      floatx4 z = {b1r, b1r, b1r, b1r};
      z = MFMA16(akf[0], whi[0], z);
      z = MFMA16(akf[1], whi[1], z);
      z = MFMA16(akf[0], wlo[0], z);
      z = MFMA16(akf[1], wlo[1], z);
      for (int r = 0; r < 4; ++r)
        Z1s[(4 * q + r) * 68 + 16 * wave + i16] = z[r];
    }
    if (wave == 0) {
      bf16x8 aq0 = *(const bf16x8*)&xqs[pb][i16 * 72 + q * 8];
      bf16x8 aq1 = *(const bf16x8*)&xqs[pb][i16 * 72 + 32 + q * 8];
      floatx4 at = {};
      at = MFMA16(aq0, akf[0], at);
      at = MFMA16(aq1, akf[1], at);
      for (int r = 0; r < 4; ++r) {
        int krow = 4 * q + r;
        float pv = (i16 <= krow) ? -(at[r] + 1.0f) * etar[r] : 0.0f;
        Pm[krow * 24 + i16] = (bf16)pv;
      }
    }
    __syncthreads();   // barrier B

    // ---- stage B: LN fused-l2 backward -> grad^T hi/lo (paired writes) ----
    {
      floatx4 z4 = *(const floatx4*)&Z1s[kr * 68 + f0];
      float tg[4], sum = 0.f, ssq = 0.f;
      for (int j = 0; j < 4; ++j) {
        tg[j] = (float)rv[j] - (float)rk[j];   // regs still hold chunk c
        sum += z4[j]; ssq += z4[j] * z4[j];
      }
      for (int m = 1; m < 16; m <<= 1) { sum += __shfl_xor(sum, m, 64); ssq += __shfl_xor(ssq, m, 64); }
      float mu = sum * (1.f / 64.f);
      float var = ssq * (1.f / 64.f) - mu * mu;
      float rstd = rsqrtf(var + 1e-6f);
      float xh[4], gx[4], s1 = 0.f, s2 = 0.f;
      for (int j = 0; j < 4; ++j) {
        xh[j] = (z4[j] - mu) * rstd;
        float go = gq[j] * xh[j] + bq[j] - tg[j];
        gx[j] = go * gq[j];
        s1 += gx[j]; s2 += gx[j] * xh[j];
      }
      for (int m = 1; m < 16; m <<= 1) { s1 += __shfl_xor(s1, m, 64); s2 += __shfl_xor(s2, m, 64); }
      unsigned hp0, hp1, lp0, lp1;
      {
        bf16 hb[4], lb[4];
        for (int j = 0; j < 4; ++j) {
          float gr = (64.f * gx[j] - s1 - xh[j] * s2) * (rstd * (1.f / 64.f));
          hb[j] = (bf16)gr;
          lb[j] = (bf16)(gr - (float)hb[j]);
        }
        hp0 = bfbits(hb[0]) | (bfbits(hb[1]) << 16);
        hp1 = bfbits(hb[2]) | (bfbits(hb[3]) << 16);
        lp0 = bfbits(lb[0]) | (bfbits(lb[1]) << 16);
        lp1 = bfbits(lb[2]) | (bfbits(lb[3]) << 16);
      }
      unsigned qh0 = (unsigned)__shfl_xor((int)hp0, 16, 64);
      unsigned qh1 = (unsigned)__shfl_xor((int)hp1, 16, 64);
      unsigned ql0 = (unsigned)__shfl_xor((int)lp0, 16, 64);
      unsigned ql1 = (unsigned)__shfl_xor((int)lp1, 16, 64);
      if (!(kr & 1)) {
        *(unsigned*)&gTh[(f0 + 0) * 24 + kr] = (hp0 & 0xffffu) | (qh0 << 16);
        *(unsigned*)&gTh[(f0 + 1) * 24 + kr] = (hp0 >> 16) | (qh0 & 0xffff0000u);
        *(unsigned*)&gTh[(f0 + 2) * 24 + kr] = (hp1 & 0xffffu) | (qh1 << 16);
        *(unsigned*)&gTh[(f0 + 3) * 24 + kr] = (hp1 >> 16) | (qh1 & 0xffff0000u);
        *(unsigned*)&gTl[(f0 + 0) * 24 + kr] = (lp0 & 0xffffu) | (ql0 << 16);
        *(unsigned*)&gTl[(f0 + 1) * 24 + kr] = (lp0 >> 16) | (ql0 & 0xffff0000u);
        *(unsigned*)&gTl[(f0 + 2) * 24 + kr] = (lp1 & 0xffffu) | (ql1 << 16);
        *(unsigned*)&gTl[(f0 + 3) * 24 + kr] = (lp1 >> 16) | (ql1 & 0xffff0000u);
      }
    }
    __syncthreads();   // barrier C

    // prefetch chunk c+1 (c=127 reads spill harmlessly into adjacent ws buffers)
    {
      const size_t cb = qbase + (size_t)(c + 1) * 1024 + kr * 64 + f0;
      rq = *(const bf16x4*)(Q  + cb);
      rk = *(const bf16x4*)(Kx + cb);
      rv = *(const bf16x4*)(V  + cb);
    }

    // ---- stage C: Z1_bar = xq@W1 + P@grad + b1 ----
    {
      bf16x8 aq0 = *(const bf16x8*)&xqs[pb][i16 * 72 + q * 8];
      bf16x8 aq1 = *(const bf16x8*)&xqs[pb][i16 * 72 + 32 + q * 8];
      bf16x8 pf  = *(const bf16x8*)&Pm[i16 * 24 + (q & 1) * 8];
      const bf16* gT = (q < 2) ? gTh : gTl;    // K=32 packing: hi halves then lo halves
      bf16x8 bgp = *(const bf16x8*)&gT[(16 * wave + i16) * 24 + (q & 1) * 8];
      floatx4 zb = {b1r, b1r, b1r, b1r};
      zb = MFMA16(aq0, whi[0], zb);
      zb = MFMA16(aq1, whi[1], zb);
      zb = MFMA16(aq0, wlo[0], zb);
      zb = MFMA16(aq1, wlo[1], zb);
      zb = MFMA16(pf, bgp, zb);                // sums P*(grad_hi+grad_lo)
      for (int r = 0; r < 4; ++r)
        Z1s[(4 * q + r) * 68 + 16 * wave + i16] = zb[r];

      // ---- stage D: W1 += -(1/16) xk^T (grad_hi+grad_lo) ; write new W1T; b1 update --
      for (int mt = 0; mt < 4; ++mt) {
        bf16x8 axk = *(const bf16x8*)&xkTs[(16 * mt + i16) * 24 + (q & 1) * 8];
        accW[mt] = MFMA16(axk, bgp, accW[mt]);
      }
      for (int mt = 0; mt < 4; ++mt) {
        bf16x4 h4, l4;
        for (int r = 0; r < 4; ++r) {
          float w = accW[mt][r];
          bf16 hi = (bf16)w;
          h4[r] = hi; l4[r] = (bf16)(w - (float)hi);
        }
        int base = (16 * wave + i16) * 72 + 16 * mt + 4 * q;
        *(bf16x4*)&W1Th[base] = h4;
        *(bf16x4*)&W1Tl[base] = l4;
      }
      {
        const bf16* rh = &gTh[(16 * wave + i16) * 24];
        const bf16* rl = &gTl[(16 * wave + i16) * 24];
        bf16x8 a0 = *(const bf16x8*)rh, a1 = *(const bf16x8*)(rh + 8);
        bf16x8 a2 = *(const bf16x8*)rl, a3 = *(const bf16x8*)(rl + 8);
        float s = 0.f;
        for (int j = 0; j < 8; ++j)
          s += (float)a0[j] + (float)a1[j] + (float)a2[j] + (float)a3[j];
        b1r -= 0.0625f * s;
      }
    }
    __syncthreads();   // barrier D

    // ---- stage E: out = xq + LN_fwd(Z1_bar) -> O (aliases Q) ----
    {
      floatx4 z4 = *(const floatx4*)&Z1s[kr * 68 + f0];
      float sum = 0.f, ssq = 0.f;
      for (int j = 0; j < 4; ++j) { sum += z4[j]; ssq += z4[j] * z4[j]; }
      for (int m = 1; m < 16; m <<= 1) { sum += __shfl_xor(sum, m, 64); ssq += __shfl_xor(ssq, m, 64); }
      float mu = sum * (1.f / 64.f);
      float var = ssq * (1.f / 64.f) - mu * mu;
      float rstd = rsqrtf(var + 1e-6f);
      bf16x4 xq4 = *(const bf16x4*)&xqs[pb][kr * 72 + f0];
      bf16x4 o4;
      for (int j = 0; j < 4; ++j)
        o4[j] = (bf16)((float)xq4[j] + gq[j] * ((z4[j] - mu) * rstd) + bq[j]);
      *(bf16x4*)(O + qbase + (size_t)c * 1024 + kr * 64 + f0) = o4;
    }
    // no barrier here: next phase-0 writes the other chunk buffer; all other
    // producer/consumer pairs are separated by barriers A-D of the next iteration.
  }
}

extern "C" void kernel_launch(void* const* d_in, const int* in_sizes, int n_in,
                              void* d_out, int out_size, void* d_ws, size_t ws_size,
                              hipStream_t stream)
{
  const float* X  = (const float*)d_in[0];
  const float* wq = (const float*)d_in[1];
  const float* wk = (const float*)d_in[2];
  const float* wv = (const float*)d_in[3];
  const float* wo = (const float*)d_in[4];
  const float* W1 = (const float*)d_in[5];
  const float* b1 = (const float*)d_in[6];
  const float* gw = (const float*)d_in[7];
  const float* gb = (const float*)d_in[8];

  bf16* ws = (bf16*)d_ws;
  const size_t NEl = (size_t)BB * LL * DD;   // 33,554,432 elems per tensor
  bf16* Qb = ws;                 // also the scan output O (aliased)
  bf16* Kb = ws + NEl;
  bf16* WT = ws + 2 * NEl;       // single 2048x2048 transposed bf16 weight slot, reused
  bf16* Vb = (bf16*)d_out;       // V bf16 (64 MB) in d_out's first half (d_out = 128 MB fp32)
  bf16* Xb = (bf16*)d_out + NEl; // X bf16 (64 MB) in d_out's second half; both are fully
                                 // consumed before the final GEMM overwrites d_out.

  cast_bf16<<<dim3(16384), 256, 0, stream>>>(X, Xb);
  transpose1<<<dim3(32, 32), 256, 0, stream>>>(wq, WT);
  gemm_bt<0, 1, 1><<<dim3(16, 128), 256, 0, stream>>>(Xb, WT, Qb);   // Q + fused RoPE
  transpose1<<<dim3(32, 32), 256, 0, stream>>>(wk, WT);
  gemm_bt<0, 1, 1><<<dim3(16, 128), 256, 0, stream>>>(Xb, WT, Kb);   // K + fused RoPE
  transpose1<<<dim3(32, 32), 256, 0, stream>>>(wv, WT);
  gemm_bt<0, 1, 0><<<dim3(16, 128), 256, 0, stream>>>(Xb, WT, Vb);   // V
  ttt_scan<<<dim3(256), 256, 0, stream>>>(Qb, Kb, Vb, W1, b1, gw, gb, Qb);
  transpose1<<<dim3(32, 32), 256, 0, stream>>>(wo, WT);
  gemm_bt<1, 0, 0><<<dim3(16, 128), 256, 0, stream>>>(Qb, WT, d_out);
}